// Round 15
// baseline (136.859 us; speedup 1.0000x reference)
//
#include <hip/hip_runtime.h>

// B=16, N1=16, TOTAL_IN=1024 (two layers of 512 x dim 8), D1=64
// softmax rows sum to 1 =>  S[b,k,l] = sum_i (1 + rowsum_bias[k,i]) * U[b,k,i,l]
// v12b = v12 with __hip_atomic_fence -> __builtin_amdgcn_fence (compile fix):
//   - grid 1024 (4 blocks/CU; capacity >= 8 -> co-residency guaranteed w/ margin)
//   - partial written/read with agent-scope atomics (bypass non-coherent XCD L2)
//   - every block tickets; blocks 0..255 spin then run the reduce+squash
//   - ctr zeroed each call via hipMemsetAsync (graph-captured, deterministic)
// (Round 14 bench lost to an unresponsive container; resubmitting unchanged.)

__global__ __launch_bounds__(256) void fused_kernel(
        const float* __restrict__ x0, const float* __restrict__ x1,
        const float* __restrict__ W0, const float* __restrict__ W1,
        const float* __restrict__ bias, float* __restrict__ partial,
        unsigned int* __restrict__ ctr, float* __restrict__ out) {
    __shared__ float xs[16 * 132];      // [i_local][b*8+j], 528B row stride
    __shared__ float ssum[16];          // per-i_local scale
    __shared__ float rbuf[4 * 8 * 64];  // [wave][bi][l] reduction scratch, 8KB
    const int tid = threadIdx.x;
    const int k     = blockIdx.x >> 6;     // [0,16)
    const int chunk = blockIdx.x & 63;     // [0,64)
    const int g  = tid >> 4;               // i_local [0,16)
    const int q  = tid & 15;               // l-quad  [0,16)
    const int w  = tid >> 6;               // wave    [0,4)
    const int gw = g & 3;                  // g within wave

    const int layer = chunk >> 5;
    const int i0    = (chunk & 31) * 16;   // i within layer
    const int ig0   = chunk * 16;          // global i
    const float* __restrict__ x = layer ? x1 : x0;
    const float* __restrict__ W = layer ? W1 : W0;

    // ---- 1. issue x loads (oldest)
    const float4* xp = (const float4*)(x + (size_t)(g * 512 + i0 + q) * 8);
    float4 a0 = xp[0], a1 = xp[1];

    // ---- 2. issue bias loads in two register batches (va freed before vb use)
    const float4* bp = (const float4*)(bias + (size_t)(k * 1024 + ig0 + g) * 1024);
    float4 va[8], vb[8];
#pragma unroll
    for (int it = 0; it < 8; ++it) va[it] = bp[q + 16 * it];
#pragma unroll
    for (int it = 0; it < 8; ++it) vb[it] = bp[q + 16 * (8 + it)];

    // ---- 3. issue W loads LAST (stay in flight across the lgkm-only barriers)
    const float4* Wf4 = (const float4*)W;
    const size_t wbase = (size_t)(k * 512 + i0 + g) * 128 + q;
    float4 wv[8];
#pragma unroll
    for (int j = 0; j < 8; ++j) wv[j] = Wf4[wbase + j * 16];
    __builtin_amdgcn_sched_barrier(0);   // pin: all loads issued before any use

    // ---- 4. bias rowsum for row ig0+g
    {
        float s0 = 0.f, s1 = 0.f, s2 = 0.f, s3 = 0.f;
#pragma unroll
        for (int it = 0; it < 8; it += 4) {
            s0 += va[it].x + va[it].y + va[it].z + va[it].w;
            s1 += va[it + 1].x + va[it + 1].y + va[it + 1].z + va[it + 1].w;
            s2 += va[it + 2].x + va[it + 2].y + va[it + 2].z + va[it + 2].w;
            s3 += va[it + 3].x + va[it + 3].y + va[it + 3].z + va[it + 3].w;
        }
#pragma unroll
        for (int it = 0; it < 8; it += 4) {
            s0 += vb[it].x + vb[it].y + vb[it].z + vb[it].w;
            s1 += vb[it + 1].x + vb[it + 1].y + vb[it + 1].z + vb[it + 1].w;
            s2 += vb[it + 2].x + vb[it + 2].y + vb[it + 2].z + vb[it + 2].w;
            s3 += vb[it + 3].x + vb[it + 3].y + vb[it + 3].z + vb[it + 3].w;
        }
        float s = (s0 + s1) + (s2 + s3);
#pragma unroll
        for (int m = 8; m >= 1; m >>= 1) s += __shfl_xor(s, m);  // 16-lane group
        if (q == 0) ssum[g] = 1.0f + s;
    }
    asm volatile("s_waitcnt lgkmcnt(0)" ::: "memory");
    __builtin_amdgcn_s_barrier();
    __builtin_amdgcn_sched_barrier(0);

    // ---- 5. stage xs[il=q][bb=g][j] = x * scale(row i0+q)
    {
        const float s = ssum[q];
        *(float4*)&xs[q * 132 + g * 8] =
            make_float4(a0.x * s, a0.y * s, a0.z * s, a0.w * s);
        *(float4*)&xs[q * 132 + g * 8 + 4] =
            make_float4(a1.x * s, a1.y * s, a1.z * s, a1.w * s);
    }
    asm volatile("s_waitcnt lgkmcnt(0)" ::: "memory");
    __builtin_amdgcn_s_barrier();
    __builtin_amdgcn_sched_barrier(0);

    // ---- 6+7. FMA over b in two halves of 8; shfl reduce; rbuf; store.
#pragma unroll
    for (int half = 0; half < 2; ++half) {
        float4 acc[8];
#pragma unroll
        for (int bi = 0; bi < 8; ++bi) acc[bi] = make_float4(0.f, 0.f, 0.f, 0.f);
#pragma unroll
        for (int bi = 0; bi < 8; ++bi) {
            const int b = half * 8 + bi;
            float xr[8];
            *(float4*)&xr[0] = *(const float4*)&xs[g * 132 + b * 8];      // broadcast
            *(float4*)&xr[4] = *(const float4*)&xs[g * 132 + b * 8 + 4];
#pragma unroll
            for (int j = 0; j < 8; ++j) {
                acc[bi].x += xr[j] * wv[j].x;
                acc[bi].y += xr[j] * wv[j].y;
                acc[bi].z += xr[j] * wv[j].z;
                acc[bi].w += xr[j] * wv[j].w;
            }
        }
#pragma unroll
        for (int bi = 0; bi < 8; ++bi) {
            acc[bi].x += __shfl_xor(acc[bi].x, 32); acc[bi].x += __shfl_xor(acc[bi].x, 16);
            acc[bi].y += __shfl_xor(acc[bi].y, 32); acc[bi].y += __shfl_xor(acc[bi].y, 16);
            acc[bi].z += __shfl_xor(acc[bi].z, 32); acc[bi].z += __shfl_xor(acc[bi].z, 16);
            acc[bi].w += __shfl_xor(acc[bi].w, 32); acc[bi].w += __shfl_xor(acc[bi].w, 16);
        }
        if (gw == 0) {
#pragma unroll
            for (int bi = 0; bi < 8; ++bi)
                *(float4*)&rbuf[(w * 8 + bi) * 64 + q * 4] = acc[bi];
        }
        __syncthreads();
        {
            const int bi = tid >> 5;
            const int l  = tid & 31;
            float v0 = 0.f, v1 = 0.f;
#pragma unroll
            for (int ww = 0; ww < 4; ++ww) {
                v0 += rbuf[(ww * 8 + bi) * 64 + l];
                v1 += rbuf[(ww * 8 + bi) * 64 + l + 32];
            }
            const int b = half * 8 + bi;
            // agent-scope stores: bypass the per-XCD L2 -> device-visible on completion
            __hip_atomic_store(&partial[(size_t)blockIdx.x * 1024 + b * 64 + l], v0,
                               __ATOMIC_RELAXED, __HIP_MEMORY_SCOPE_AGENT);
            __hip_atomic_store(&partial[(size_t)blockIdx.x * 1024 + b * 64 + l + 32], v1,
                               __ATOMIC_RELAXED, __HIP_MEMORY_SCOPE_AGENT);
        }
        __syncthreads();   // protect rbuf rewrite; drains vmcnt (stores complete)
    }

    // ---- 8. device-scope ticket barrier
    if (tid == 0) {
        __builtin_amdgcn_fence(__ATOMIC_RELEASE, "agent");
        __hip_atomic_fetch_add(ctr, 1u, __ATOMIC_ACQ_REL, __HIP_MEMORY_SCOPE_AGENT);
    }
    if (blockIdx.x >= 256) return;

    if (tid == 0) {
        while (__hip_atomic_load(ctr, __ATOMIC_RELAXED, __HIP_MEMORY_SCOPE_AGENT) < 1024u)
            __builtin_amdgcn_s_sleep(2);
    }
    __syncthreads();
    __builtin_amdgcn_fence(__ATOMIC_ACQUIRE, "agent");

    // ---- 9. reduce + squash for row = blockIdx.x  (rbuf reused as scratch)
    {
        const int row = blockIdx.x;         // [0,256) = b*16 + k
        const int rb = row >> 4, rk = row & 15;
        const int lane = tid & 63;
        float s = 0.f;
#pragma unroll
        for (int cc = 0; cc < 16; ++cc) {
            const int c = w + cc * 4;       // wave-interleaved chunks [0,64)
            s += __hip_atomic_load(&partial[((size_t)(rk * 64 + c)) * 1024 + rb * 64 + lane],
                                   __ATOMIC_RELAXED, __HIP_MEMORY_SCOPE_AGENT);
        }
        rbuf[w * 64 + lane] = s;
        __syncthreads();
        if (w == 0) {
            float v = rbuf[0 * 64 + lane] + rbuf[1 * 64 + lane] +
                      rbuf[2 * 64 + lane] + rbuf[3 * 64 + lane];
            float sq = v * v;
#pragma unroll
            for (int m = 32; m >= 1; m >>= 1) sq += __shfl_xor(sq, m);
            out[(size_t)row * 64 + lane] = (sq / (1.0f + sq)) * v / (sqrtf(sq) + 1e-5f);
        }
    }
}

// ---------------------------------------------------------------------------
extern "C" void kernel_launch(void* const* d_in, const int* in_sizes, int n_in,
                              void* d_out, int out_size, void* d_ws, size_t ws_size,
                              hipStream_t stream) {
    const float* x0  = (const float*)d_in[0];   // [16,512,8]
    const float* x1  = (const float*)d_in[1];   // [16,512,8]
    const float* W0  = (const float*)d_in[2];   // [16,512,8,64]
    const float* W1  = (const float*)d_in[3];   // [16,512,8,64]
    const float* bia = (const float*)d_in[4];   // [16,1024,1024]
    float* out = (float*)d_out;                 // [16,16,64]

    float* partial    = (float*)d_ws;           // 1024*1024 floats = 4 MB
    unsigned int* ctr = (unsigned int*)((char*)d_ws + (size_t)1024 * 1024 * 4);

    (void)hipMemsetAsync(ctr, 0, sizeof(unsigned int), stream);  // graph-captured reset
    fused_kernel<<<dim3(1024), dim3(256), 0, stream>>>(x0, x1, W0, W1, bia,
                                                       partial, ctr, out);
}

// Round 16
// 27.440 us; speedup vs baseline: 4.9876x; 4.9876x over previous
//
#include <hip/hip_runtime.h>

// B=16, N1=16, TOTAL_IN=1024 (two layers of 512 x dim 8), D1=64
// softmax rows sum to 1 =>  S[b,k,l] = sum_i (1 + rowsum_bias[k,i]) * U[b,k,i,l]
// v13 = v10 RESTORED (best measured: 27.65 us). v12b's device-barrier fusion
// regressed 5x (agent-scope atomics bypass L2; grid-wide spin serializes).
//   - bias in two 8-float4 batches (va summed+freed before vb consumed)
//   - issue order x -> bias -> W; lgkm-only barriers keep W in flight
//   - __launch_bounds__(256, 4) clamps VGPR <= 128

__global__ __launch_bounds__(256, 4) void proj_kernel(
        const float* __restrict__ x0, const float* __restrict__ x1,
        const float* __restrict__ W0, const float* __restrict__ W1,
        const float* __restrict__ bias, float* __restrict__ partial) {
    __shared__ float xs[16 * 132];      // [i_local][b*8+j], 528B row stride
    __shared__ float ssum[16];          // per-i_local scale
    __shared__ float rbuf[4 * 8 * 64];  // [wave][bi][l] cross-wave reduction, 8KB
    const int tid = threadIdx.x;
    const int k     = blockIdx.x >> 6;     // [0,16)
    const int chunk = blockIdx.x & 63;     // [0,64)
    const int g  = tid >> 4;               // i_local [0,16)
    const int q  = tid & 15;               // l-quad  [0,16)
    const int w  = tid >> 6;               // wave    [0,4)
    const int gw = g & 3;                  // g within wave

    const int layer = chunk >> 5;
    const int i0    = (chunk & 31) * 16;   // i within layer
    const int ig0   = chunk * 16;          // global i
    const float* __restrict__ x = layer ? x1 : x0;
    const float* __restrict__ W = layer ? W1 : W0;

    // ---- 1. issue x loads (oldest)
    const float4* xp = (const float4*)(x + (size_t)(g * 512 + i0 + q) * 8);
    float4 a0 = xp[0], a1 = xp[1];

    // ---- 2. issue bias loads in two register batches (va freed before vb use)
    const float4* bp = (const float4*)(bias + (size_t)(k * 1024 + ig0 + g) * 1024);
    float4 va[8], vb[8];
#pragma unroll
    for (int it = 0; it < 8; ++it) va[it] = bp[q + 16 * it];
#pragma unroll
    for (int it = 0; it < 8; ++it) vb[it] = bp[q + 16 * (8 + it)];

    // ---- 3. issue W loads LAST (newest: stay in flight across both barriers)
    // float4 index of W[k][i0+g][j][q*4] = (k*512+i0+g)*128 + j*16 + q
    const float4* Wf4 = (const float4*)W;
    const size_t wbase = (size_t)(k * 512 + i0 + g) * 128 + q;
    float4 wv[8];
#pragma unroll
    for (int j = 0; j < 8; ++j) wv[j] = Wf4[wbase + j * 16];
    __builtin_amdgcn_sched_barrier(0);   // pin: all loads issued before any use

    // ---- 4. bias rowsum for row ig0+g: consume va (frees 32 VGPR), then vb
    {
        float s0 = 0.f, s1 = 0.f, s2 = 0.f, s3 = 0.f;
#pragma unroll
        for (int it = 0; it < 8; it += 4) {
            s0 += va[it].x + va[it].y + va[it].z + va[it].w;
            s1 += va[it + 1].x + va[it + 1].y + va[it + 1].z + va[it + 1].w;
            s2 += va[it + 2].x + va[it + 2].y + va[it + 2].z + va[it + 2].w;
            s3 += va[it + 3].x + va[it + 3].y + va[it + 3].z + va[it + 3].w;
        }
#pragma unroll
        for (int it = 0; it < 8; it += 4) {
            s0 += vb[it].x + vb[it].y + vb[it].z + vb[it].w;
            s1 += vb[it + 1].x + vb[it + 1].y + vb[it + 1].z + vb[it + 1].w;
            s2 += vb[it + 2].x + vb[it + 2].y + vb[it + 2].z + vb[it + 2].w;
            s3 += vb[it + 3].x + vb[it + 3].y + vb[it + 3].z + vb[it + 3].w;
        }
        float s = (s0 + s1) + (s2 + s3);
#pragma unroll
        for (int m = 8; m >= 1; m >>= 1) s += __shfl_xor(s, m);  // 16-lane group
        if (q == 0) ssum[g] = 1.0f + s;
    }
    // lgkm-only barrier: ssum visible; W loads remain in flight
    asm volatile("s_waitcnt lgkmcnt(0)" ::: "memory");
    __builtin_amdgcn_s_barrier();
    __builtin_amdgcn_sched_barrier(0);

    // ---- 5. stage xs[il=q][bb=g][j] = x * scale(row i0+q)
    {
        const float s = ssum[q];
        *(float4*)&xs[q * 132 + g * 8] =
            make_float4(a0.x * s, a0.y * s, a0.z * s, a0.w * s);
        *(float4*)&xs[q * 132 + g * 8 + 4] =
            make_float4(a1.x * s, a1.y * s, a1.z * s, a1.w * s);
    }
    // lgkm-only barrier again: W still in flight
    asm volatile("s_waitcnt lgkmcnt(0)" ::: "memory");
    __builtin_amdgcn_s_barrier();
    __builtin_amdgcn_sched_barrier(0);

    // ---- 6+7. FMA over b in two halves of 8 (wv[j] consumed with progressive
    //           vmcnt as W returns); wave-shfl reduce; rbuf; store.
#pragma unroll
    for (int half = 0; half < 2; ++half) {
        float4 acc[8];
#pragma unroll
        for (int bi = 0; bi < 8; ++bi) acc[bi] = make_float4(0.f, 0.f, 0.f, 0.f);
#pragma unroll
        for (int bi = 0; bi < 8; ++bi) {
            const int b = half * 8 + bi;
            float xr[8];
            *(float4*)&xr[0] = *(const float4*)&xs[g * 132 + b * 8];      // broadcast
            *(float4*)&xr[4] = *(const float4*)&xs[g * 132 + b * 8 + 4];
#pragma unroll
            for (int j = 0; j < 8; ++j) {
                acc[bi].x += xr[j] * wv[j].x;
                acc[bi].y += xr[j] * wv[j].y;
                acc[bi].z += xr[j] * wv[j].z;
                acc[bi].w += xr[j] * wv[j].w;
            }
        }
        // reduce over the 4 g-rows in this wave (lane bits 4,5)
#pragma unroll
        for (int bi = 0; bi < 8; ++bi) {
            acc[bi].x += __shfl_xor(acc[bi].x, 32); acc[bi].x += __shfl_xor(acc[bi].x, 16);
            acc[bi].y += __shfl_xor(acc[bi].y, 32); acc[bi].y += __shfl_xor(acc[bi].y, 16);
            acc[bi].z += __shfl_xor(acc[bi].z, 32); acc[bi].z += __shfl_xor(acc[bi].z, 16);
            acc[bi].w += __shfl_xor(acc[bi].w, 32); acc[bi].w += __shfl_xor(acc[bi].w, 16);
        }
        if (gw == 0) {
            // each wave writes its own disjoint rbuf region
#pragma unroll
            for (int bi = 0; bi < 8; ++bi)
                *(float4*)&rbuf[(w * 8 + bi) * 64 + q * 4] = acc[bi];
        }
        __syncthreads();   // all loads consumed by now: vmcnt drain is free
        // cross-wave sum: thread -> (bi = tid>>5, l = tid&31 and +32)
        {
            const int bi = tid >> 5;
            const int l  = tid & 31;
            float v0 = 0.f, v1 = 0.f;
#pragma unroll
            for (int ww = 0; ww < 4; ++ww) {
                v0 += rbuf[(ww * 8 + bi) * 64 + l];
                v1 += rbuf[(ww * 8 + bi) * 64 + l + 32];
            }
            const int b = half * 8 + bi;
            partial[(size_t)blockIdx.x * 1024 + b * 64 + l]      = v0;
            partial[(size_t)blockIdx.x * 1024 + b * 64 + l + 32] = v1;
        }
        __syncthreads();   // protect rbuf rewrite in next half
    }
}

// ---------------------------------------------------------------------------
// One block per (b,k) row: S[b,k,l] = sum over 64 chunk partials; squash.
__global__ __launch_bounds__(256) void reduce_squash_kernel(
        const float* __restrict__ partial, float* __restrict__ out) {
    __shared__ float red[4][64];
    const int row = blockIdx.x;            // [0,256) = b*16 + k
    const int b = row >> 4, k = row & 15;
    const int w = threadIdx.x >> 6, lane = threadIdx.x & 63;
    float s = 0.f;
#pragma unroll
    for (int cc = 0; cc < 16; ++cc) {
        const int c = w + cc * 4;          // wave-interleaved chunks [0,64)
        s += partial[((size_t)(k * 64 + c)) * 1024 + b * 64 + lane];
    }
    red[w][lane] = s;
    __syncthreads();
    if (w == 0) {
        float v = red[0][lane] + red[1][lane] + red[2][lane] + red[3][lane];
        float sq = v * v;
#pragma unroll
        for (int m = 32; m >= 1; m >>= 1) sq += __shfl_xor(sq, m);
        out[(size_t)row * 64 + lane] = (sq / (1.0f + sq)) * v / (sqrtf(sq) + 1e-5f);
    }
}

// ---------------------------------------------------------------------------
extern "C" void kernel_launch(void* const* d_in, const int* in_sizes, int n_in,
                              void* d_out, int out_size, void* d_ws, size_t ws_size,
                              hipStream_t stream) {
    const float* x0  = (const float*)d_in[0];   // [16,512,8]
    const float* x1  = (const float*)d_in[1];   // [16,512,8]
    const float* W0  = (const float*)d_in[2];   // [16,512,8,64]
    const float* W1  = (const float*)d_in[3];   // [16,512,8,64]
    const float* bia = (const float*)d_in[4];   // [16,1024,1024]
    float* out = (float*)d_out;                 // [16,16,64]

    float* partial = (float*)d_ws;              // 1024*1024 floats = 4 MB

    proj_kernel<<<dim3(1024), dim3(256), 0, stream>>>(x0, x1, W0, W1, bia, partial);
    reduce_squash_kernel<<<dim3(256), dim3(256), 0, stream>>>(partial, out);
}